// Round 5
// baseline (286.842 us; speedup 1.0000x reference)
//
#include <hip/hip_runtime.h>
#include <stdint.h>

#define Bv 4
#define Sv 2048
#define Dv 512
#define Hv 8
#define E3 1536  // 3*D
#define PPITCH 164  // P strip pitch (u16): 82 dwords -> 4-quad rows land on 4 distinct bank bases

typedef unsigned short u16;
typedef __bf16 bf16x8 __attribute__((ext_vector_type(8)));
typedef float f32x4 __attribute__((ext_vector_type(4)));

// fp32 -> bf16 RNE
__device__ __forceinline__ u16 f2b(float f) {
  union { float f; uint32_t u; } v; v.f = f;
  uint32_t r = v.u + 0x7FFFu + ((v.u >> 16) & 1u);
  return (u16)(r >> 16);
}

// async global->LDS, 16B per lane; LDS dest must be wave-uniform base (+lane*16 implicit)
__device__ __forceinline__ void gl_lds16(const void* g, void* l) {
  __builtin_amdgcn_global_load_lds(
      (__attribute__((address_space(1))) void*)(uintptr_t)g,
      (__attribute__((address_space(3))) void*)(uintptr_t)l, 16, 0, 0);
}

// all three fp32->bf16 casts in one launch (ranges are exact multiples of 256)
__global__ __launch_bounds__(256) void k_cast3(const float* __restrict__ x,
                                               const float* __restrict__ wqkv,
                                               const float* __restrict__ wo,
                                               u16* __restrict__ xb,
                                               u16* __restrict__ wqkvb,
                                               u16* __restrict__ wob) {
  const int bid = blockIdx.x;
  const float* in; u16* out; int i;
  if (bid < 2048)      { in = x;    out = xb;    i = bid * 256 + threadIdx.x; }
  else if (bid < 2432) { in = wqkv; out = wqkvb; i = (bid - 2048) * 256 + threadIdx.x; }
  else                 { in = wo;   out = wob;   i = (bid - 2432) * 256 + threadIdx.x; }
  const float4* p = (const float4*)in;
  float4 a = p[(size_t)i * 2], b = p[(size_t)i * 2 + 1];
  union { u16 h[8]; uint4 v; } r;
  r.h[0] = f2b(a.x); r.h[1] = f2b(a.y); r.h[2] = f2b(a.z); r.h[3] = f2b(a.w);
  r.h[4] = f2b(b.x); r.h[5] = f2b(b.y); r.h[6] = f2b(b.z); r.h[7] = f2b(b.w);
  ((uint4*)out)[i] = r.v;
}

// C[M][N] = A[M][K] * Bw[N][K]^T + bias, m97-style 128x128 tile, BK=32.
template <int OUTF32>
__global__ __launch_bounds__(256) void k_gemm_bt(const u16* __restrict__ A,
                                                 const u16* __restrict__ Bw,
                                                 const float* __restrict__ bias,
                                                 void* __restrict__ C, int N, int K) {
  __shared__ alignas(16) u16 As[128][32];
  __shared__ alignas(16) u16 Bs[128][32];
  const int tid = threadIdx.x, lane = tid & 63, w = tid >> 6;
  const int quad = lane >> 4, l16 = lane & 15;
  const int wm = w & 1, wn = w >> 1;
  const size_t m0 = (size_t)blockIdx.y * 128;
  const int n0 = blockIdx.x * 128;
  const int srow = lane >> 2, scol = (lane & 3) * 8;
  f32x4 acc[4][4] = {};
  for (int k0 = 0; k0 < K; k0 += 32) {
    #pragma unroll
    for (int c = 0; c < 2; ++c) {
      const int rb = (w * 2 + c) * 16;
      gl_lds16(A + (m0 + rb + srow) * K + k0 + scol, &As[rb][0]);
      gl_lds16(Bw + (size_t)(n0 + rb + srow) * K + k0 + scol, &Bs[rb][0]);
    }
    __syncthreads();
    bf16x8 af[4], bfr[4];
    #pragma unroll
    for (int t = 0; t < 4; ++t) {
      af[t]  = *(const bf16x8*)&As[wm * 64 + t * 16 + l16][quad * 8];
      bfr[t] = *(const bf16x8*)&Bs[wn * 64 + t * 16 + l16][quad * 8];
    }
    #pragma unroll
    for (int mt = 0; mt < 4; ++mt)
      #pragma unroll
      for (int nt = 0; nt < 4; ++nt)
        acc[mt][nt] = __builtin_amdgcn_mfma_f32_16x16x32_bf16(af[mt], bfr[nt],
                                                              acc[mt][nt], 0, 0, 0);
    __syncthreads();
  }
  #pragma unroll
  for (int nt = 0; nt < 4; ++nt) {
    const int col = n0 + wn * 64 + nt * 16 + l16;
    const float bv = bias[col];
    #pragma unroll
    for (int mt = 0; mt < 4; ++mt) {
      const size_t row = m0 + wm * 64 + mt * 16 + quad * 4;
      #pragma unroll
      for (int r = 0; r < 4; ++r) {
        float v = acc[mt][nt][r] + bv;
        if (OUTF32) ((float*)C)[(row + r) * N + col] = v;
        else        ((u16*)C)[(row + r) * N + col] = f2b(v);
      }
    }
  }
}

// Pack K and V into lane-linear MFMA fragment layouts + build mask bias.
__global__ __launch_bounds__(256) void k_pack(const u16* __restrict__ qkv,
                                              const int* __restrict__ mask,
                                              u16* __restrict__ kp,
                                              u16* __restrict__ vp,
                                              float* __restrict__ mbias) {
  __shared__ alignas(16) u16 T[64][72];
  const int tid = threadIdx.x;
  const int bh = blockIdx.y, b = bh >> 3, h = bh & 7;
  const int s0 = blockIdx.x * 64;
  if (h == 0 && tid < 64) {
    const int s = b * Sv + s0 + tid;
    mbias[s] = mask[s] ? 0.0f : -1e30f;
  }
  const size_t kpb = (size_t)bh * 128 * 1024;
  for (int idx = tid; idx < 512; idx += 256) {
    int r = idx >> 3, c8 = idx & 7;
    uint4 d = *(const uint4*)(qkv + (size_t)(b * Sv + s0 + r) * E3 + h * 192 + 64 + c8 * 8);
    int tile = (s0 >> 4) + (r >> 4), half = c8 >> 2, quad = c8 & 3, l16 = r & 15;
    *(uint4*)(kp + kpb + (size_t)tile * 1024 + half * 512 + (quad * 16 + l16) * 8) = d;
  }
  for (int idx = tid; idx < 512; idx += 256) {
    int r = idx >> 3, c = idx & 7;
    *(uint4*)&T[r][c * 8] =
        *(const uint4*)(qkv + ((size_t)(b * Sv + s0 + r)) * E3 + h * 192 + 128 + c * 8);
  }
  __syncthreads();
  const size_t vpb = (size_t)bh * 64 * 2048;
  for (int idx = tid; idx < 512; idx += 256) {
    int cc = idx >> 8, rest = idx & 255, dh = rest >> 2, kq = rest & 3;
    union { u16 h[8]; uint4 v; } rr;
    #pragma unroll
    for (int j = 0; j < 8; ++j) rr.h[j] = T[cc * 32 + kq * 8 + j][dh];
    int chunk = (s0 >> 5) + cc, nt2 = dh >> 4;
    *(uint4*)(vp + vpb + ((size_t)(chunk * 4 + nt2)) * 512 + (kq * 16 + (dh & 15)) * 8) = rr.v;
  }
}

// Barrier-free flash attention with 2-way KV split (flash-decoding style):
// block = 4 waves = 2 q-strips x 2 KV halves; no online max -> partials
// combine by plain addition (O=O0+O1, L=L0+L1) through LDS, one barrier.
// 8192 waves total -> grid no longer caps occupancy.
__global__ __launch_bounds__(256, 7) void k_attn(const u16* __restrict__ qkv,
                                                 const u16* __restrict__ kp,
                                                 const u16* __restrict__ vp,
                                                 const float* __restrict__ mbias,
                                                 u16* __restrict__ vals) {
  __shared__ alignas(16) u16 Ps[4][16 * PPITCH];  // per-wave P strip / combine buffer
  const int tid = threadIdx.x, lane = tid & 63, w = tid >> 6;
  const int quad = lane >> 4, l16 = lane & 15;
  const int bh = blockIdx.y, b = bh >> 3, h = bh & 7;
  const int sidx = (blockIdx.x << 1) | (w & 1);  // q-strip 0..127 within (b,h)
  const int half = w >> 1;                        // KV half
  const int q0 = sidx * 16;

  const u16* qrow = qkv + (size_t)(b * Sv + q0 + l16) * E3 + h * 192 + quad * 8;
  bf16x8 aq0 = *(const bf16x8*)qrow;
  bf16x8 aq1 = *(const bf16x8*)(qrow + 32);

  bf16x8 bones;
  {
    union { u16 u; __bf16 b; } one; one.u = 0x3F80;  // 1.0 bf16
    #pragma unroll
    for (int j = 0; j < 8; ++j) bones[j] = one.b;
  }

  f32x4 La = {0.f, 0.f, 0.f, 0.f};
  f32x4 Oa[4] = {};

  const u16* kpb = kp + (size_t)bh * 128 * 1024 + lane * 8;
  const u16* vpb = vp + (size_t)bh * 64 * 2048 + lane * 8;
  const float* mrow = mbias + b * Sv + l16;
  u16* ps_w = &Ps[w][0];
  const float cs = 0.18033688011112042f;  // 0.125 * log2(e)
  const int k_begin = half * (Sv / 2), k_end = k_begin + Sv / 2;

  #pragma unroll 1
  for (int k0 = k_begin; k0 < k_end; k0 += 128) {
    const int t0 = k0 >> 4, c0 = k0 >> 5;
    // S = Q K^T for 128 keys (frags lane-linear from kp)
    f32x4 Sa[8] = {};
    #pragma unroll
    for (int nt = 0; nt < 8; ++nt) {
      const u16* tb = kpb + (size_t)(t0 + nt) * 1024;
      bf16x8 bk0 = *(const bf16x8*)tb;
      bf16x8 bk1 = *(const bf16x8*)(tb + 512);
      Sa[nt] = __builtin_amdgcn_mfma_f32_16x16x32_bf16(aq0, bk0, Sa[nt], 0, 0, 0);
      Sa[nt] = __builtin_amdgcn_mfma_f32_16x16x32_bf16(aq1, bk1, Sa[nt], 0, 0, 0);
    }
    // P = exp2(S*cs + mb) -> bf16 (truncate; bias cancels in p/l) -> LDS strip
    #pragma unroll
    for (int nt = 0; nt < 8; ++nt) {
      const float mb = mrow[k0 + nt * 16];
      #pragma unroll
      for (int r = 0; r < 4; ++r) {
        union { float f; uint32_t u; } pv;
        pv.f = __builtin_amdgcn_exp2f(fmaf(Sa[nt][r], cs, mb));
        ps_w[(quad * 4 + r) * PPITCH + nt * 16 + l16] = (u16)(pv.u >> 16);
      }
    }
    // O += P V ; l += P * ones  (same-wave LDS round trip, no barrier)
    #pragma unroll
    for (int ks = 0; ks < 4; ++ks) {
      bf16x8 ap = *(const bf16x8*)(ps_w + l16 * PPITCH + ks * 32 + quad * 8);
      La = __builtin_amdgcn_mfma_f32_16x16x32_bf16(ap, bones, La, 0, 0, 0);
      #pragma unroll
      for (int nt2 = 0; nt2 < 4; ++nt2) {
        bf16x8 bv8 = *(const bf16x8*)(vpb + (size_t)((c0 + ks) * 4 + nt2) * 512);
        Oa[nt2] = __builtin_amdgcn_mfma_f32_16x16x32_bf16(ap, bv8, Oa[nt2], 0, 0, 0);
      }
    }
  }

  // combine the two KV halves of each strip (plain addition; no max-merge)
  if (half == 1) {
    f32x4* fl = (f32x4*)((float*)&Ps[w][0] + lane * 20);
    fl[0] = Oa[0]; fl[1] = Oa[1]; fl[2] = Oa[2]; fl[3] = Oa[3]; fl[4] = La;
  }
  __syncthreads();
  if (half == 0) {
    const f32x4* fl = (const f32x4*)((const float*)&Ps[w + 2][0] + lane * 20);
    #pragma unroll
    for (int i = 0; i < 4; ++i) Oa[i] += fl[i];
    La += fl[4];
    float li[4];
    #pragma unroll
    for (int r = 0; r < 4; ++r) li[r] = 1.0f / La[r];
    #pragma unroll
    for (int nt2 = 0; nt2 < 4; ++nt2)
      #pragma unroll
      for (int r = 0; r < 4; ++r) {
        const size_t srow = (size_t)(b * Sv + q0 + quad * 4 + r);
        vals[srow * Dv + h * 64 + nt2 * 16 + l16] = f2b(Oa[nt2][r] * li[r]);
      }
  }
}

extern "C" void kernel_launch(void* const* d_in, const int* in_sizes, int n_in,
                              void* d_out, int out_size, void* d_ws, size_t ws_size,
                              hipStream_t stream) {
  const float* x    = (const float*)d_in[0];
  const int*   mask = (const int*)d_in[1];
  const float* Wqkv = (const float*)d_in[2];
  const float* bqkv = (const float*)d_in[3];
  const float* Wo   = (const float*)d_in[4];
  const float* bo   = (const float*)d_in[5];
  float* out = (float*)d_out;

  char* ws = (char*)d_ws;
  u16* xb    = (u16*)(ws + 0);                    //  8,388,608  x bf16 (dead after QKV gemm)
  u16* wqkvb = (u16*)(ws + 8388608);              //  1,572,864  W_qkv bf16 (dead after QKV gemm)
  u16* wob   = (u16*)(ws + 9961472);              //    524,288  W_o bf16
  u16* qkv   = (u16*)(ws + 10485760);             // 25,165,824  qkv bf16 [8192][1536]
  u16* kp    = (u16*)(ws + 35651584);             //  8,388,608  packed K frags
  u16* vals  = (u16*)(ws + 44040192);             //  8,388,608  attn out bf16 [8192][512]
  u16* vp    = (u16*)(ws + 0);                    //  8,388,608  packed V frags (reuses xb)
  float* mbias = (float*)(ws + 8388608);          //     32,768  mask bias (reuses wqkvb)

  k_cast3<<<2560, 256, 0, stream>>>(x, Wqkv, Wo, xb, wqkvb, wob);
  k_gemm_bt<0><<<dim3(12, 64), 256, 0, stream>>>(xb, wqkvb, bqkv, qkv, E3, Dv);
  k_pack<<<dim3(32, 32), 256, 0, stream>>>(qkv, mask, kp, vp, mbias);
  k_attn<<<dim3(64, 32), 256, 0, stream>>>(qkv, kp, vp, mbias, vals);
  k_gemm_bt<1><<<dim3(4, 64), 256, 0, stream>>>(vals, wob, bo, out, Dv, Dv);
}

// Round 6
// 205.585 us; speedup vs baseline: 1.3952x; 1.3952x over previous
//
#include <hip/hip_runtime.h>
#include <stdint.h>

#define Bv 4
#define Sv 2048
#define Dv 512
#define Hv 8
#define E3 1536  // 3*D
#define PPITCH 164  // P strip pitch (u16)

typedef unsigned short u16;
typedef __bf16 bf16x8 __attribute__((ext_vector_type(8)));
typedef float f32x4 __attribute__((ext_vector_type(4)));

// fp32 -> bf16 RNE
__device__ __forceinline__ u16 f2b(float f) {
  union { float f; uint32_t u; } v; v.f = f;
  uint32_t r = v.u + 0x7FFFu + ((v.u >> 16) & 1u);
  return (u16)(r >> 16);
}

// async global->LDS, 16B per lane; LDS dest must be wave-uniform base (+lane*16 implicit)
__device__ __forceinline__ void gl_lds16(const void* g, void* l) {
  __builtin_amdgcn_global_load_lds(
      (__attribute__((address_space(1))) void*)(uintptr_t)g,
      (__attribute__((address_space(3))) void*)(uintptr_t)l, 16, 0, 0);
}

// all three fp32->bf16 casts in one launch (ranges are exact multiples of 256)
__global__ __launch_bounds__(256) void k_cast3(const float* __restrict__ x,
                                               const float* __restrict__ wqkv,
                                               const float* __restrict__ wo,
                                               u16* __restrict__ xb,
                                               u16* __restrict__ wqkvb,
                                               u16* __restrict__ wob) {
  const int bid = blockIdx.x;
  const float* in; u16* out; int i;
  if (bid < 2048)      { in = x;    out = xb;    i = bid * 256 + threadIdx.x; }
  else if (bid < 2432) { in = wqkv; out = wqkvb; i = (bid - 2048) * 256 + threadIdx.x; }
  else                 { in = wo;   out = wob;   i = (bid - 2432) * 256 + threadIdx.x; }
  const float4* p = (const float4*)in;
  float4 a = p[(size_t)i * 2], b = p[(size_t)i * 2 + 1];
  union { u16 h[8]; uint4 v; } r;
  r.h[0] = f2b(a.x); r.h[1] = f2b(a.y); r.h[2] = f2b(a.z); r.h[3] = f2b(a.w);
  r.h[4] = f2b(b.x); r.h[5] = f2b(b.y); r.h[6] = f2b(b.z); r.h[7] = f2b(b.w);
  ((uint4*)out)[i] = r.v;
}

// C[M][N] = A[M][K] * Bw[N][K]^T + bias, m97-style 128x128 tile, BK=32.
template <int OUTF32>
__global__ __launch_bounds__(256) void k_gemm_bt(const u16* __restrict__ A,
                                                 const u16* __restrict__ Bw,
                                                 const float* __restrict__ bias,
                                                 void* __restrict__ C, int N, int K) {
  __shared__ alignas(16) u16 As[128][32];
  __shared__ alignas(16) u16 Bs[128][32];
  const int tid = threadIdx.x, lane = tid & 63, w = tid >> 6;
  const int quad = lane >> 4, l16 = lane & 15;
  const int wm = w & 1, wn = w >> 1;
  const size_t m0 = (size_t)blockIdx.y * 128;
  const int n0 = blockIdx.x * 128;
  const int srow = lane >> 2, scol = (lane & 3) * 8;
  f32x4 acc[4][4] = {};
  for (int k0 = 0; k0 < K; k0 += 32) {
    #pragma unroll
    for (int c = 0; c < 2; ++c) {
      const int rb = (w * 2 + c) * 16;
      gl_lds16(A + (m0 + rb + srow) * K + k0 + scol, &As[rb][0]);
      gl_lds16(Bw + (size_t)(n0 + rb + srow) * K + k0 + scol, &Bs[rb][0]);
    }
    __syncthreads();
    bf16x8 af[4], bfr[4];
    #pragma unroll
    for (int t = 0; t < 4; ++t) {
      af[t]  = *(const bf16x8*)&As[wm * 64 + t * 16 + l16][quad * 8];
      bfr[t] = *(const bf16x8*)&Bs[wn * 64 + t * 16 + l16][quad * 8];
    }
    #pragma unroll
    for (int mt = 0; mt < 4; ++mt)
      #pragma unroll
      for (int nt = 0; nt < 4; ++nt)
        acc[mt][nt] = __builtin_amdgcn_mfma_f32_16x16x32_bf16(af[mt], bfr[nt],
                                                              acc[mt][nt], 0, 0, 0);
    __syncthreads();
  }
  #pragma unroll
  for (int nt = 0; nt < 4; ++nt) {
    const int col = n0 + wn * 64 + nt * 16 + l16;
    const float bv = bias[col];
    #pragma unroll
    for (int mt = 0; mt < 4; ++mt) {
      const size_t row = m0 + wm * 64 + mt * 16 + quad * 4;
      #pragma unroll
      for (int r = 0; r < 4; ++r) {
        float v = acc[mt][nt][r] + bv;
        if (OUTF32) ((float*)C)[(row + r) * N + col] = v;
        else        ((u16*)C)[(row + r) * N + col] = f2b(v);
      }
    }
  }
}

// Pack K and V into lane-linear MFMA fragment layouts + build mask bias.
__global__ __launch_bounds__(256) void k_pack(const u16* __restrict__ qkv,
                                              const int* __restrict__ mask,
                                              u16* __restrict__ kp,
                                              u16* __restrict__ vp,
                                              float* __restrict__ mbias) {
  __shared__ alignas(16) u16 T[64][72];
  const int tid = threadIdx.x;
  const int bh = blockIdx.y, b = bh >> 3, h = bh & 7;
  const int s0 = blockIdx.x * 64;
  if (h == 0 && tid < 64) {
    const int s = b * Sv + s0 + tid;
    mbias[s] = mask[s] ? 0.0f : -1e30f;
  }
  const size_t kpb = (size_t)bh * 128 * 1024;
  for (int idx = tid; idx < 512; idx += 256) {
    int r = idx >> 3, c8 = idx & 7;
    uint4 d = *(const uint4*)(qkv + (size_t)(b * Sv + s0 + r) * E3 + h * 192 + 64 + c8 * 8);
    int tile = (s0 >> 4) + (r >> 4), half = c8 >> 2, quad = c8 & 3, l16 = r & 15;
    *(uint4*)(kp + kpb + (size_t)tile * 1024 + half * 512 + (quad * 16 + l16) * 8) = d;
  }
  for (int idx = tid; idx < 512; idx += 256) {
    int r = idx >> 3, c = idx & 7;
    *(uint4*)&T[r][c * 8] =
        *(const uint4*)(qkv + ((size_t)(b * Sv + s0 + r)) * E3 + h * 192 + 128 + c * 8);
  }
  __syncthreads();
  const size_t vpb = (size_t)bh * 64 * 2048;
  for (int idx = tid; idx < 512; idx += 256) {
    int cc = idx >> 8, rest = idx & 255, dh = rest >> 2, kq = rest & 3;
    union { u16 h[8]; uint4 v; } rr;
    #pragma unroll
    for (int j = 0; j < 8; ++j) rr.h[j] = T[cc * 32 + kq * 8 + j][dh];
    int chunk = (s0 >> 5) + cc, nt2 = dh >> 4;
    *(uint4*)(vp + vpb + ((size_t)(chunk * 4 + nt2)) * 512 + (kq * 16 + (dh & 15)) * 8) = rr.v;
  }
}

// Barrier-free flash attention with 2-way KV split (flash-decoding style):
// block = 4 waves = 2 q-strips x 2 KV halves; no online max -> partials
// combine by plain addition (O=O0+O1, L=L0+L1) through LDS, one barrier.
// launch_bounds(256,4): VGPR cap 128 -- kernel wants ~72, DO NOT tighten
// further (256,7 forced VGPR=36 -> 160 MB/dispatch scratch spill, R5).
__global__ __launch_bounds__(256, 4) void k_attn(const u16* __restrict__ qkv,
                                                 const u16* __restrict__ kp,
                                                 const u16* __restrict__ vp,
                                                 const float* __restrict__ mbias,
                                                 u16* __restrict__ vals) {
  __shared__ alignas(16) u16 Ps[4][16 * PPITCH];  // per-wave P strip / combine buffer
  const int tid = threadIdx.x, lane = tid & 63, w = tid >> 6;
  const int quad = lane >> 4, l16 = lane & 15;
  const int bh = blockIdx.y, b = bh >> 3, h = bh & 7;
  const int sidx = (blockIdx.x << 1) | (w & 1);  // q-strip 0..127 within (b,h)
  const int half = w >> 1;                        // KV half
  const int q0 = sidx * 16;

  const u16* qrow = qkv + (size_t)(b * Sv + q0 + l16) * E3 + h * 192 + quad * 8;
  bf16x8 aq0 = *(const bf16x8*)qrow;
  bf16x8 aq1 = *(const bf16x8*)(qrow + 32);

  bf16x8 bones;
  {
    union { u16 u; __bf16 b; } one; one.u = 0x3F80;  // 1.0 bf16
    #pragma unroll
    for (int j = 0; j < 8; ++j) bones[j] = one.b;
  }

  f32x4 La = {0.f, 0.f, 0.f, 0.f};
  f32x4 Oa[4] = {};

  const u16* kpb = kp + (size_t)bh * 128 * 1024 + lane * 8;
  const u16* vpb = vp + (size_t)bh * 64 * 2048 + lane * 8;
  const float* mrow = mbias + b * Sv + l16;
  u16* ps_w = &Ps[w][0];
  const float cs = 0.18033688011112042f;  // 0.125 * log2(e)
  const int k_begin = half * (Sv / 2), k_end = k_begin + Sv / 2;

  #pragma unroll 1
  for (int k0 = k_begin; k0 < k_end; k0 += 128) {
    const int t0 = k0 >> 4, c0 = k0 >> 5;
    // S = Q K^T for 128 keys (frags lane-linear from kp)
    f32x4 Sa[8] = {};
    #pragma unroll
    for (int nt = 0; nt < 8; ++nt) {
      const u16* tb = kpb + (size_t)(t0 + nt) * 1024;
      bf16x8 bk0 = *(const bf16x8*)tb;
      bf16x8 bk1 = *(const bf16x8*)(tb + 512);
      Sa[nt] = __builtin_amdgcn_mfma_f32_16x16x32_bf16(aq0, bk0, Sa[nt], 0, 0, 0);
      Sa[nt] = __builtin_amdgcn_mfma_f32_16x16x32_bf16(aq1, bk1, Sa[nt], 0, 0, 0);
    }
    // P = exp2(S*cs + mb) -> bf16 (truncate; bias cancels in p/l) -> LDS strip
    #pragma unroll
    for (int nt = 0; nt < 8; ++nt) {
      const float mb = mrow[k0 + nt * 16];
      #pragma unroll
      for (int r = 0; r < 4; ++r) {
        union { float f; uint32_t u; } pv;
        pv.f = __builtin_amdgcn_exp2f(fmaf(Sa[nt][r], cs, mb));
        ps_w[(quad * 4 + r) * PPITCH + nt * 16 + l16] = (u16)(pv.u >> 16);
      }
    }
    // O += P V ; l += P * ones  (same-wave LDS round trip, no barrier)
    #pragma unroll
    for (int ks = 0; ks < 4; ++ks) {
      bf16x8 ap = *(const bf16x8*)(ps_w + l16 * PPITCH + ks * 32 + quad * 8);
      La = __builtin_amdgcn_mfma_f32_16x16x32_bf16(ap, bones, La, 0, 0, 0);
      #pragma unroll
      for (int nt2 = 0; nt2 < 4; ++nt2) {
        bf16x8 bv8 = *(const bf16x8*)(vpb + (size_t)((c0 + ks) * 4 + nt2) * 512);
        Oa[nt2] = __builtin_amdgcn_mfma_f32_16x16x32_bf16(ap, bv8, Oa[nt2], 0, 0, 0);
      }
    }
  }

  // combine the two KV halves of each strip (plain addition; no max-merge)
  if (half == 1) {
    f32x4* fl = (f32x4*)((float*)&Ps[w][0] + lane * 20);
    fl[0] = Oa[0]; fl[1] = Oa[1]; fl[2] = Oa[2]; fl[3] = Oa[3]; fl[4] = La;
  }
  __syncthreads();
  if (half == 0) {
    const f32x4* fl = (const f32x4*)((const float*)&Ps[w + 2][0] + lane * 20);
    #pragma unroll
    for (int i = 0; i < 4; ++i) Oa[i] += fl[i];
    La += fl[4];
    float li[4];
    #pragma unroll
    for (int r = 0; r < 4; ++r) li[r] = 1.0f / La[r];
    #pragma unroll
    for (int nt2 = 0; nt2 < 4; ++nt2)
      #pragma unroll
      for (int r = 0; r < 4; ++r) {
        const size_t srow = (size_t)(b * Sv + q0 + quad * 4 + r);
        vals[srow * Dv + h * 64 + nt2 * 16 + l16] = f2b(Oa[nt2][r] * li[r]);
      }
  }
}

extern "C" void kernel_launch(void* const* d_in, const int* in_sizes, int n_in,
                              void* d_out, int out_size, void* d_ws, size_t ws_size,
                              hipStream_t stream) {
  const float* x    = (const float*)d_in[0];
  const int*   mask = (const int*)d_in[1];
  const float* Wqkv = (const float*)d_in[2];
  const float* bqkv = (const float*)d_in[3];
  const float* Wo   = (const float*)d_in[4];
  const float* bo   = (const float*)d_in[5];
  float* out = (float*)d_out;

  char* ws = (char*)d_ws;
  u16* xb    = (u16*)(ws + 0);                    //  8,388,608  x bf16 (dead after QKV gemm)
  u16* wqkvb = (u16*)(ws + 8388608);              //  1,572,864  W_qkv bf16 (dead after QKV gemm)
  u16* wob   = (u16*)(ws + 9961472);              //    524,288  W_o bf16
  u16* qkv   = (u16*)(ws + 10485760);             // 25,165,824  qkv bf16 [8192][1536]
  u16* kp    = (u16*)(ws + 35651584);             //  8,388,608  packed K frags
  u16* vals  = (u16*)(ws + 44040192);             //  8,388,608  attn out bf16 [8192][512]
  u16* vp    = (u16*)(ws + 0);                    //  8,388,608  packed V frags (reuses xb)
  float* mbias = (float*)(ws + 8388608);          //     32,768  mask bias (reuses wqkvb)

  k_cast3<<<2560, 256, 0, stream>>>(x, Wqkv, Wo, xb, wqkvb, wob);
  k_gemm_bt<0><<<dim3(12, 64), 256, 0, stream>>>(xb, wqkvb, bqkv, qkv, E3, Dv);
  k_pack<<<dim3(32, 32), 256, 0, stream>>>(qkv, mask, kp, vp, mbias);
  k_attn<<<dim3(64, 32), 256, 0, stream>>>(qkv, kp, vp, mbias, vals);
  k_gemm_bt<1><<<dim3(4, 64), 256, 0, stream>>>(vals, wob, bo, out, Dv, Dv);
}

// Round 7
// 202.555 us; speedup vs baseline: 1.4161x; 1.0150x over previous
//
#include <hip/hip_runtime.h>
#include <stdint.h>

#define Bv 4
#define Sv 2048
#define Dv 512
#define Hv 8
#define E3 1536  // 3*D
#define PPITCH 164  // P strip pitch (u16)

typedef unsigned short u16;
typedef __bf16 bf16x8 __attribute__((ext_vector_type(8)));
typedef float f32x4 __attribute__((ext_vector_type(4)));

// fp32 -> bf16 RNE
__device__ __forceinline__ u16 f2b(float f) {
  union { float f; uint32_t u; } v; v.f = f;
  uint32_t r = v.u + 0x7FFFu + ((v.u >> 16) & 1u);
  return (u16)(r >> 16);
}

// async global->LDS, 16B per lane; LDS dest must be wave-uniform base (+lane*16 implicit)
__device__ __forceinline__ void gl_lds16(const void* g, void* l) {
  __builtin_amdgcn_global_load_lds(
      (__attribute__((address_space(1))) void*)(uintptr_t)g,
      (__attribute__((address_space(3))) void*)(uintptr_t)l, 16, 0, 0);
}

// fp32->bf16 casts for x / W_qkv / W_o + mask bias build, one launch
__global__ __launch_bounds__(256) void k_cast3(const float* __restrict__ x,
                                               const float* __restrict__ wqkv,
                                               const float* __restrict__ wo,
                                               const int* __restrict__ mask,
                                               u16* __restrict__ xb,
                                               u16* __restrict__ wqkvb,
                                               u16* __restrict__ wob,
                                               float* __restrict__ mbias) {
  const int bid = blockIdx.x;
  if (bid >= 2560) {  // mask bias: 8192 ints in 32 blocks
    const int i = (bid - 2560) * 256 + threadIdx.x;
    mbias[i] = mask[i] ? 0.0f : -1e30f;
    return;
  }
  const float* in; u16* out; int i;
  if (bid < 2048)      { in = x;    out = xb;    i = bid * 256 + threadIdx.x; }
  else if (bid < 2432) { in = wqkv; out = wqkvb; i = (bid - 2048) * 256 + threadIdx.x; }
  else                 { in = wo;   out = wob;   i = (bid - 2432) * 256 + threadIdx.x; }
  const float4* p = (const float4*)in;
  float4 a = p[(size_t)i * 2], b = p[(size_t)i * 2 + 1];
  union { u16 h[8]; uint4 v; } r;
  r.h[0] = f2b(a.x); r.h[1] = f2b(a.y); r.h[2] = f2b(a.z); r.h[3] = f2b(a.w);
  r.h[4] = f2b(b.x); r.h[5] = f2b(b.y); r.h[6] = f2b(b.z); r.h[7] = f2b(b.w);
  ((uint4*)out)[i] = r.v;
}

// C[M][N] = A[M][K] * Bw[N][K]^T + bias, m97-style 128x128 tile, BK=32.
template <int OUTF32>
__global__ __launch_bounds__(256) void k_gemm_bt(const u16* __restrict__ A,
                                                 const u16* __restrict__ Bw,
                                                 const float* __restrict__ bias,
                                                 void* __restrict__ C, int N, int K) {
  __shared__ alignas(16) u16 As[128][32];
  __shared__ alignas(16) u16 Bs[128][32];
  const int tid = threadIdx.x, lane = tid & 63, w = tid >> 6;
  const int quad = lane >> 4, l16 = lane & 15;
  const int wm = w & 1, wn = w >> 1;
  const size_t m0 = (size_t)blockIdx.y * 128;
  const int n0 = blockIdx.x * 128;
  const int srow = lane >> 2, scol = (lane & 3) * 8;
  f32x4 acc[4][4] = {};
  for (int k0 = 0; k0 < K; k0 += 32) {
    #pragma unroll
    for (int c = 0; c < 2; ++c) {
      const int rb = (w * 2 + c) * 16;
      gl_lds16(A + (m0 + rb + srow) * K + k0 + scol, &As[rb][0]);
      gl_lds16(Bw + (size_t)(n0 + rb + srow) * K + k0 + scol, &Bs[rb][0]);
    }
    __syncthreads();
    bf16x8 af[4], bfr[4];
    #pragma unroll
    for (int t = 0; t < 4; ++t) {
      af[t]  = *(const bf16x8*)&As[wm * 64 + t * 16 + l16][quad * 8];
      bfr[t] = *(const bf16x8*)&Bs[wn * 64 + t * 16 + l16][quad * 8];
    }
    #pragma unroll
    for (int mt = 0; mt < 4; ++mt)
      #pragma unroll
      for (int nt = 0; nt < 4; ++nt)
        acc[mt][nt] = __builtin_amdgcn_mfma_f32_16x16x32_bf16(af[mt], bfr[nt],
                                                              acc[mt][nt], 0, 0, 0);
    __syncthreads();
  }
  #pragma unroll
  for (int nt = 0; nt < 4; ++nt) {
    const int col = n0 + wn * 64 + nt * 16 + l16;
    const float bv = bias[col];
    #pragma unroll
    for (int mt = 0; mt < 4; ++mt) {
      const size_t row = m0 + wm * 64 + mt * 16 + quad * 4;
      #pragma unroll
      for (int r = 0; r < 4; ++r) {
        float v = acc[mt][nt][r] + bv;
        if (OUTF32) ((float*)C)[(row + r) * N + col] = v;
        else        ((u16*)C)[(row + r) * N + col] = f2b(v);
      }
    }
  }
}

// Pack K and V into lane-linear MFMA fragment layouts.
__global__ __launch_bounds__(256) void k_pack(const u16* __restrict__ qkv,
                                              u16* __restrict__ kp,
                                              u16* __restrict__ vp) {
  __shared__ alignas(16) u16 T[64][72];
  const int tid = threadIdx.x;
  const int bh = blockIdx.y, b = bh >> 3, h = bh & 7;
  const int s0 = blockIdx.x * 64;
  const size_t kpb = (size_t)bh * 128 * 1024;
  for (int idx = tid; idx < 512; idx += 256) {
    int r = idx >> 3, c8 = idx & 7;
    uint4 d = *(const uint4*)(qkv + (size_t)(b * Sv + s0 + r) * E3 + h * 192 + 64 + c8 * 8);
    int tile = (s0 >> 4) + (r >> 4), half = c8 >> 2, quad = c8 & 3, l16 = r & 15;
    *(uint4*)(kp + kpb + (size_t)tile * 1024 + half * 512 + (quad * 16 + l16) * 8) = d;
  }
  for (int idx = tid; idx < 512; idx += 256) {
    int r = idx >> 3, c = idx & 7;
    *(uint4*)&T[r][c * 8] =
        *(const uint4*)(qkv + ((size_t)(b * Sv + s0 + r)) * E3 + h * 192 + 128 + c * 8);
  }
  __syncthreads();
  const size_t vpb = (size_t)bh * 64 * 2048;
  for (int idx = tid; idx < 512; idx += 256) {
    int cc = idx >> 8, rest = idx & 255, dh = rest >> 2, kq = rest & 3;
    union { u16 h[8]; uint4 v; } rr;
    #pragma unroll
    for (int j = 0; j < 8; ++j) rr.h[j] = T[cc * 32 + kq * 8 + j][dh];
    int chunk = (s0 >> 5) + cc, nt2 = dh >> 4;
    *(uint4*)(vp + vpb + ((size_t)(chunk * 4 + nt2)) * 512 + (kq * 16 + (dh & 15)) * 8) = rr.v;
  }
}

// Flash attention, 4-way KV split: block = 1 q-strip x 4 quarter-waves.
// No online max -> partials combine by plain addition through LDS (1 barrier).
// bid = bh + 32*strip so all blocks of one (b,h) share an XCD (L2 locality).
// V frags hoisted ahead of the exp/P phase to overlap global latency.
// launch_bounds(256,4): VGPR cap 128 (256,7 forced 36 -> massive spill, R5).
__global__ __launch_bounds__(256, 4) void k_attn(const u16* __restrict__ qkv,
                                                 const u16* __restrict__ kp,
                                                 const u16* __restrict__ vp,
                                                 const float* __restrict__ mbias,
                                                 u16* __restrict__ vals) {
  __shared__ alignas(16) u16 Ps[4][16 * PPITCH];  // per-wave P strip / combine buffer
  const int tid = threadIdx.x, lane = tid & 63, w = tid >> 6;
  const int quad = lane >> 4, l16 = lane & 15;
  const int bid = blockIdx.x;
  const int bh = bid & 31, strip = bid >> 5;
  const int b = bh >> 3, h = bh & 7;
  const int q0 = strip * 16;

  const u16* qrow = qkv + (size_t)(b * Sv + q0 + l16) * E3 + h * 192 + quad * 8;
  bf16x8 aq0 = *(const bf16x8*)qrow;
  bf16x8 aq1 = *(const bf16x8*)(qrow + 32);

  bf16x8 bones;
  {
    union { u16 u; __bf16 b; } one; one.u = 0x3F80;  // 1.0 bf16
    #pragma unroll
    for (int j = 0; j < 8; ++j) bones[j] = one.b;
  }

  f32x4 La = {0.f, 0.f, 0.f, 0.f};
  f32x4 Oa[4] = {};

  const u16* kpb = kp + (size_t)bh * 128 * 1024 + lane * 8;
  const u16* vpb = vp + (size_t)bh * 64 * 2048 + lane * 8;
  const float* mrow = mbias + b * Sv + l16;
  u16* ps_w = &Ps[w][0];
  const float cs = 0.18033688011112042f;  // 0.125 * log2(e)
  const int k_begin = w * (Sv / 4), k_end = k_begin + Sv / 4;

  #pragma unroll 1
  for (int k0 = k_begin; k0 < k_end; k0 += 128) {
    const int t0 = k0 >> 4, c0 = k0 >> 5;
    // hoist first-half V frags (latency overlaps QK + exp phases)
    bf16x8 vv[2][4];
    #pragma unroll
    for (int ks = 0; ks < 2; ++ks)
      #pragma unroll
      for (int nt2 = 0; nt2 < 4; ++nt2)
        vv[ks][nt2] = *(const bf16x8*)(vpb + (size_t)((c0 + ks) * 4 + nt2) * 512);
    // S = Q K^T for 128 keys (frags lane-linear from kp)
    f32x4 Sa[8] = {};
    #pragma unroll
    for (int nt = 0; nt < 8; ++nt) {
      const u16* tb = kpb + (size_t)(t0 + nt) * 1024;
      bf16x8 bk0 = *(const bf16x8*)tb;
      bf16x8 bk1 = *(const bf16x8*)(tb + 512);
      Sa[nt] = __builtin_amdgcn_mfma_f32_16x16x32_bf16(aq0, bk0, Sa[nt], 0, 0, 0);
      Sa[nt] = __builtin_amdgcn_mfma_f32_16x16x32_bf16(aq1, bk1, Sa[nt], 0, 0, 0);
    }
    // P = exp2(S*cs + mb) -> bf16 (truncate; bias cancels in p/l) -> LDS strip
    #pragma unroll
    for (int nt = 0; nt < 8; ++nt) {
      const float mb = mrow[k0 + nt * 16];
      #pragma unroll
      for (int r = 0; r < 4; ++r) {
        union { float f; uint32_t u; } pv;
        pv.f = __builtin_amdgcn_exp2f(fmaf(Sa[nt][r], cs, mb));
        ps_w[(quad * 4 + r) * PPITCH + nt * 16 + l16] = (u16)(pv.u >> 16);
      }
    }
    // second-half V frags (latency overlaps P-store drain + first PV MFMAs)
    bf16x8 vv2[2][4];
    #pragma unroll
    for (int ks = 0; ks < 2; ++ks)
      #pragma unroll
      for (int nt2 = 0; nt2 < 4; ++nt2)
        vv2[ks][nt2] = *(const bf16x8*)(vpb + (size_t)((c0 + 2 + ks) * 4 + nt2) * 512);
    // O += P V ; l += P * ones  (same-wave LDS round trip, no barrier)
    #pragma unroll
    for (int ks = 0; ks < 4; ++ks) {
      bf16x8 ap = *(const bf16x8*)(ps_w + l16 * PPITCH + ks * 32 + quad * 8);
      La = __builtin_amdgcn_mfma_f32_16x16x32_bf16(ap, bones, La, 0, 0, 0);
      #pragma unroll
      for (int nt2 = 0; nt2 < 4; ++nt2) {
        bf16x8 bv8 = (ks < 2) ? vv[ks][nt2] : vv2[ks - 2][nt2];
        Oa[nt2] = __builtin_amdgcn_mfma_f32_16x16x32_bf16(ap, bv8, Oa[nt2], 0, 0, 0);
      }
    }
  }

  // combine the four KV quarters (plain addition; no max-merge)
  if (w != 0) {
    f32x4* fl = (f32x4*)((float*)&Ps[w][0] + lane * 20);
    fl[0] = Oa[0]; fl[1] = Oa[1]; fl[2] = Oa[2]; fl[3] = Oa[3]; fl[4] = La;
  }
  __syncthreads();
  if (w == 0) {
    #pragma unroll
    for (int j = 1; j < 4; ++j) {
      const f32x4* fl = (const f32x4*)((const float*)&Ps[j][0] + lane * 20);
      #pragma unroll
      for (int i = 0; i < 4; ++i) Oa[i] += fl[i];
      La += fl[4];
    }
    float li[4];
    #pragma unroll
    for (int r = 0; r < 4; ++r) li[r] = 1.0f / La[r];
    #pragma unroll
    for (int nt2 = 0; nt2 < 4; ++nt2)
      #pragma unroll
      for (int r = 0; r < 4; ++r) {
        const size_t srow = (size_t)(b * Sv + q0 + quad * 4 + r);
        vals[srow * Dv + h * 64 + nt2 * 16 + l16] = f2b(Oa[nt2][r] * li[r]);
      }
  }
}

extern "C" void kernel_launch(void* const* d_in, const int* in_sizes, int n_in,
                              void* d_out, int out_size, void* d_ws, size_t ws_size,
                              hipStream_t stream) {
  const float* x    = (const float*)d_in[0];
  const int*   mask = (const int*)d_in[1];
  const float* Wqkv = (const float*)d_in[2];
  const float* bqkv = (const float*)d_in[3];
  const float* Wo   = (const float*)d_in[4];
  const float* bo   = (const float*)d_in[5];
  float* out = (float*)d_out;

  char* ws = (char*)d_ws;
  u16* xb    = (u16*)(ws + 0);                    //  8,388,608  x bf16 (dead after QKV gemm)
  u16* wqkvb = (u16*)(ws + 8388608);              //  1,572,864  W_qkv bf16 (dead after QKV gemm)
  u16* wob   = (u16*)(ws + 9961472);              //    524,288  W_o bf16
  u16* qkv   = (u16*)(ws + 10485760);             // 25,165,824  qkv bf16 [8192][1536]
  u16* kp    = (u16*)(ws + 35651584);             //  8,388,608  packed K frags
  u16* vals  = (u16*)(ws + 44040192);             //  8,388,608  attn out bf16 [8192][512]
  u16* vp    = (u16*)(ws + 0);                    //  8,388,608  packed V frags (reuses xb)
  float* mbias = (float*)(ws + 52428800);         //     32,768  mask bias

  k_cast3<<<2592, 256, 0, stream>>>(x, Wqkv, Wo, mask, xb, wqkvb, wob, mbias);
  k_gemm_bt<0><<<dim3(12, 64), 256, 0, stream>>>(xb, wqkvb, bqkv, qkv, E3, Dv);
  k_pack<<<dim3(32, 32), 256, 0, stream>>>(qkv, kp, vp);
  k_attn<<<4096, 256, 0, stream>>>(qkv, kp, vp, mbias, vals);
  k_gemm_bt<1><<<dim3(4, 64), 256, 0, stream>>>(vals, wob, bo, out, Dv, Dv);
}